// Round 20
// baseline (290.621 us; speedup 1.0000x reference)
//
#include <hip/hip_runtime.h>
#include <hip/hip_bf16.h>
#include <hip/hip_fp16.h>

static constexpr int NN = 1000000;   // nodes
static constexpr int NE = 5000000;   // edges
static constexpr int NG = 4096;      // graphs
static constexpr int BIN_SH = 8;                      // 256 nodes per bin
static constexpr int BIN_SZ = 1 << BIN_SH;            // 256
static constexpr int NB = (NN + BIN_SZ - 1) >> BIN_SH;   // 3907 (last bin = 64 nodes, %64==0)
static constexpr int CAP_SH = 11;                     // 2048 edge slots per bin
static constexpr int CAP = 1 << CAP_SH;
static constexpr int EPB = 16384;                     // edges per block for the scatter pass
static constexpr int EPW = EPB / 1024;                // 16 edges per thread in scatter
static constexpr int BIN_BLOCKS = (NE + EPB - 1) / EPB;  // 306 (1024-thread blocks)
static constexpr int CHUNKW = 128;                    // edges per WAVE chunk (2/thread)
static constexpr float KEXP = 2.8853900817779268f;    // 2*log2(e): tanh(v)=1-2/(2^(K v)+1)

__device__ __forceinline__ float exp2_fast(float x) {
#if __has_builtin(__builtin_amdgcn_exp2f)
    return __builtin_amdgcn_exp2f(x);
#else
    return exp2f(x);
#endif
}

// tanh from pre-scaled argument s = KEXP * v: tanh(v) = 1 - 2/(2^s + 1).
__device__ __forceinline__ float tanh_scaled(float s) {
    float e = exp2_fast(s);
    return fmaf(-2.0f, __frcp_rn(e + 1.0f), 1.0f);
}

// full-precision tanh for the node-phase (argument not pre-scaled)
__device__ __forceinline__ float fast_tanh(float x) {
    float e = __expf(2.0f * x);
    return 1.0f - 2.0f * __fdividef(1.0f, e + 1.0f);
}

// ---- Pass 1: x->fp16 pack (grid-stride prologue) + scatter (rl,col) into bins ----
__global__ __launch_bounds__(1024) void bin_scatter_k(
    const int* __restrict__ row, const int* __restrict__ col,
    const float* __restrict__ x,
    int* __restrict__ binCursor, unsigned int* __restrict__ pack,
    __half* __restrict__ xh)
{
    __shared__ int hist[NB];          // 15.6 KB -> 2 blocks/CU
    // x -> fp16x4 pack (independent of the edge phase; consumed by bucket_agg)
    for (int i = blockIdx.x * 1024 + threadIdx.x; i < NN; i += BIN_BLOCKS * 1024) {
        union { __half2 h2[2]; uint2 u; } o;
        o.h2[0] = __floats2half2_rn(x[3 * i + 0], x[3 * i + 1]);
        o.h2[1] = __floats2half2_rn(x[3 * i + 2], 0.0f);
        *reinterpret_cast<uint2*>(xh + 4 * (size_t)i) = o.u;
    }

    for (int i = threadIdx.x; i < NB; i += 1024) hist[i] = 0;
    __syncthreads();
    int base = blockIdx.x * EPB;

    int r[EPW], c[EPW];
    bool val[EPW];
#pragma unroll
    for (int k = 0; k < EPW; ++k) {
        int e = base + k * 1024 + threadIdx.x;
        val[k] = e < NE;
        r[k] = val[k] ? row[e] : 0;
        c[k] = val[k] ? col[e] : 0;
    }
#pragma unroll
    for (int k = 0; k < EPW; ++k)
        if (val[k]) atomicAdd(&hist[r[k] >> BIN_SH], 1);
    __syncthreads();
    // hist[bin] becomes this block's ABSOLUTE write cursor for that bin
    for (int i = threadIdx.x; i < NB; i += 1024) {
        int cc = hist[i];
        hist[i] = cc ? ((i << CAP_SH) + atomicAdd(&binCursor[i], cc)) : 0;
    }
    __syncthreads();
    int pos[EPW];
#pragma unroll
    for (int k = 0; k < EPW; ++k)
        if (val[k]) pos[k] = atomicAdd(&hist[r[k] >> BIN_SH], 1);   // 16 outstanding
#pragma unroll
    for (int k = 0; k < EPW; ++k)
        if (val[k]) pack[pos[k]] = ((unsigned int)(r[k] & (BIN_SZ - 1)) << 20)
                                   | (unsigned int)c[k];
}

// prefetch one wave-chunk (2 edges/lane) of pack + xh gathers into registers
#define PREFETCH_W(CS2, GX0, GX1, RL0, RL1)                                       \
    {                                                                             \
        RL0 = RL1 = -1;                                                           \
        int cs2_ = (CS2);                                                         \
        if (cs2_ < ee) {                                                          \
            int mm_ = min(CHUNKW, ee - cs2_);                                     \
            if (lane < mm_) {                                                     \
                unsigned int p_ = pack[cs2_ + lane];                              \
                RL0 = (int)(p_ >> 20);                                            \
                GX0 = *reinterpret_cast<const uint2*>(xh + 4 * (size_t)(p_ & 0xFFFFFu)); \
            }                                                                     \
            if (64 + lane < mm_) {                                                \
                unsigned int p_ = pack[cs2_ + 64 + lane];                         \
                RL1 = (int)(p_ >> 20);                                            \
                GX1 = *reinterpret_cast<const uint2*>(xh + 4 * (size_t)(p_ & 0xFFFFFu)); \
            }                                                                     \
        }                                                                         \
    }

// ---- Pass 2: WAVE-AUTONOMOUS per-bin pipeline — ZERO barriers ----
// Each wave owns one bin: hist/scan/sort/accumulate are wave-synchronous, so
// waves never rendezvous and each wave's depth-2 gather pipeline runs free.
// Thread t owns nodes {t, 64+t, 128+t, 192+t}: acc slot k aligns with pooling
// round k (lane l <-> node 64k+l).
__global__ __launch_bounds__(256) void bucket_agg_k(
    const unsigned int* __restrict__ pack,
    const int* __restrict__ binCursor,   // final per-bin counts
    const __half* __restrict__ xh,  // [NN,4]
    const int* __restrict__ batch,
    const float* __restrict__ w1,   // [3,16]
    const float* __restrict__ b1,   // [16]
    const float* __restrict__ w2,   // [16,16]
    const float* __restrict__ b2,   // [16]
    float* __restrict__ h_sum,      // [NG,16]
    unsigned int* __restrict__ h_max, // [NG,16] monotone-encoded
    int* __restrict__ cnt)          // [NG]
{
    __shared__ uint4 payA[4][CHUNKW * 2];   // 4 KB per wave
    __shared__ int scntA[4][BIN_SZ];        // 1 KB per wave
    __shared__ int sstartA[4][BIN_SZ];      // 1 KB per wave  (24 KB/block total)

    int tid = threadIdx.x;
    int lane = tid & 63, wid = tid >> 6;
    uint4* pay = payA[wid];
    int* scnt = scntA[wid];
    int* sstart = sstartA[wid];

    int b = blockIdx.x * 4 + wid;
    if (b >= NB) return;                    // whole wave exits; no barriers anywhere
    int nodeBase = b << BIN_SH;
    int nNodes = min(BIN_SZ, NN - nodeBase);   // 256, or 64 for last bin (%64==0)
    int es = b << CAP_SH;
    int ee = es + binCursor[b];

    // one-time: bias pre-scaled by KEXP
    float b1s[16];
#pragma unroll
    for (int j = 0; j < 16; ++j) b1s[j] = b1[j] * KEXP;

    __half2 acc[4][8];                      // node 64k+lane -> acc[k][*]
#pragma unroll
    for (int k = 0; k < 4; ++k)
#pragma unroll
        for (int q = 0; q < 8; ++q) acc[k][q] = __half2half2(__float2half(0.0f));
    int dg[4] = {0, 0, 0, 0};

    // prefetch chunks 0 and 1
    uint2 gxA0, gxA1, gxB0, gxB1;
    int rlA0, rlA1, rlB0, rlB1;
    PREFETCH_W(es,           gxA0, gxA1, rlA0, rlA1);
    PREFETCH_W(es + CHUNKW,  gxB0, gxB1, rlB0, rlB1);

    for (int cs = es; cs < ee; cs += CHUNKW) {
        int m = min(CHUNKW, ee - cs);

        // zero scnt (4 contiguous ints per lane), then hist current chunk
        *reinterpret_cast<int4*>(&scnt[4 * lane]) = make_int4(0, 0, 0, 0);
        if (rlA0 >= 0) atomicAdd(&scnt[rlA0], 1);
        if (rlA1 >= 0) atomicAdd(&scnt[rlA1], 1);

        // issue chunk i+2 prefetch: no barrier will ever drain it
        uint2 gxC0, gxC1;
        int rlC0, rlC1;
        PREFETCH_W(cs + 2 * CHUNKW, gxC0, gxC1, rlC0, rlC1);

        // wave-synchronous exclusive scan of scnt[256] (4 ints/lane + shuffles)
        __builtin_amdgcn_wave_barrier();    // compiler ordering fence (free)
        int4 v4 = *reinterpret_cast<int4*>(&scnt[4 * lane]);
        int tsum = v4.x + v4.y + v4.z + v4.w;
        int sc = tsum;
#pragma unroll
        for (int off = 1; off < 64; off <<= 1) {
            int u = __shfl_up(sc, off);
            if (lane >= off) sc += u;
        }
        int ex = sc - tsum;
        int4 st;
        st.x = ex;
        st.y = st.x + v4.x;
        st.z = st.y + v4.y;
        st.w = st.z + v4.z;
        *reinterpret_cast<int4*>(&sstart[4 * lane]) = st;
        *reinterpret_cast<int4*>(&scnt[4 * lane]) = st;     // becomes cursor
        __builtin_amdgcn_wave_barrier();

        // edge-parallel MLP1 + tanh, counting-sort scatter into pay
#pragma unroll
        for (int k = 0; k < 2; ++k) {
            int rlk = k ? rlA1 : rlA0;
            if (rlk >= 0) {
                union { uint2 u; __half2 h2[2]; } xi;
                xi.u = k ? gxA1 : gxA0;
                float2 x01 = __half22float2(xi.h2[0]);
                float xs0 = x01.x * KEXP;
                float xs1 = x01.y * KEXP;
                float xs2 = __low2float(xi.h2[1]) * KEXP;
                union { __half2 h2[8]; uint4 u[2]; } o;
#pragma unroll
                for (int q = 0; q < 8; ++q) {
                    float va = fmaf(xs2, w1[32 + 2 * q], fmaf(xs1, w1[16 + 2 * q],
                               fmaf(xs0, w1[2 * q], b1s[2 * q])));
                    float vb = fmaf(xs2, w1[33 + 2 * q], fmaf(xs1, w1[17 + 2 * q],
                               fmaf(xs0, w1[2 * q + 1], b1s[2 * q + 1])));
                    o.h2[q] = __floats2half2_rn(tanh_scaled(va), tanh_scaled(vb));
                }
                int pos = atomicAdd(&scnt[rlk], 1);   // returning ds_add_rtn
                pay[2 * pos + 0] = o.u[0];
                pay[2 * pos + 1] = o.u[1];
            }
        }
        __builtin_amdgcn_wave_barrier();

        // owner accumulation: thread owns nodes {64k+lane}, k=0..3
#pragma unroll
        for (int k = 0; k < 4; ++k) {
            int node = 64 * k + lane;
            if (node < nNodes) {
                int s0 = sstart[node];
                int e0 = (node < 255) ? sstart[node + 1] : m;
                dg[k] += e0 - s0;
                for (int e = s0; e < e0; ++e) {
                    union { uint4 u; __half2 h2[4]; } ua, ub;
                    ua.u = pay[2 * e + 0];
                    ub.u = pay[2 * e + 1];
#pragma unroll
                    for (int q = 0; q < 4; ++q) {
                        acc[k][q] = __hadd2(acc[k][q], ua.h2[q]);
                        acc[k][4 + q] = __hadd2(acc[k][4 + q], ub.h2[q]);
                    }
                }
            }
        }
        __builtin_amdgcn_wave_barrier();    // pay/scnt reuse next iter

        // rotate pipeline: A <- B <- C
        gxA0 = gxB0; gxA1 = gxB1; rlA0 = rlB0; rlA1 = rlB1;
        gxB0 = gxC0; gxB1 = gxC1; rlB0 = rlC0; rlB1 = rlC1;
    }

    // node phase: 4 rounds; round k = nodes 64k..64k+63, acc slot k
#pragma unroll
    for (int k = 0; k < 4; ++k) {
        if (64 * k >= nNodes) break;        // wave-uniform
        float af[16];
#pragma unroll
        for (int q = 0; q < 8; ++q) {
            float2 f = __half22float2(acc[k][q]);
            af[2 * q + 0] = f.x;
            af[2 * q + 1] = f.y;
        }
        float inv = 1.0f / fmaxf((float)dg[k], 1.0f);
        float s[16];
#pragma unroll
        for (int j = 0; j < 16; ++j) s[j] = b2[j];
#pragma unroll
        for (int kk = 0; kk < 16; ++kk) {
            float a = af[kk] * inv;
#pragma unroll
            for (int j = 0; j < 16; ++j) s[j] = fmaf(a, w2[16 * kk + j], s[j]);
        }
        float mx[16];
#pragma unroll
        for (int j = 0; j < 16; ++j) { s[j] = fast_tanh(s[j]); mx[j] = s[j]; }

        int g = batch[nodeBase + 64 * k + lane];
        int gp = __shfl_up(g, 1);
        int head = (lane == 0) || (g != gp);
        unsigned long long hm = __ballot(head != 0);

        int f = head;
#pragma unroll
        for (int off = 1; off < 64; off <<= 1) {
            int fu = __shfl_up(f, off);
            bool take = (lane >= off) && (f == 0);
#pragma unroll
            for (int j = 0; j < 16; ++j) {
                float su = __shfl_up(s[j], off);
                float mu = __shfl_up(mx[j], off);
                if (take) { s[j] += su; mx[j] = fmaxf(mx[j], mu); }
            }
            if (lane >= off) f |= fu;
        }

        int hnext = __shfl_down(head, 1);
        bool is_last = (lane == 63) || (hnext != 0);
        if (is_last) {
            unsigned long long below = hm & (~0ULL >> (63 - lane));
            int start = 63 - __clzll(below);
            int seglen = lane - start + 1;
#pragma unroll
            for (int j = 0; j < 16; ++j) {
                unsafeAtomicAdd(&h_sum[16 * g + j], s[j]);
                atomicMax(&h_max[16 * g + j], __float_as_uint(mx[j] + 2.0f));
            }
            atomicAdd(&cnt[g], seglen);
        }
    }
}

// ---- Pass 3: head ----
__global__ __launch_bounds__(256) void out_k(
    const float* __restrict__ h_sum,
    const unsigned int* __restrict__ h_max,
    const int* __restrict__ cnt,
    const float* __restrict__ w3,   // [32]
    const float* __restrict__ b3,   // [1]
    float* __restrict__ out)        // [NG]
{
    int g = blockIdx.x * 256 + threadIdx.x;
    if (g >= NG) return;
    float invc = 1.0f / fmaxf((float)cnt[g], 1.0f);
    float acc = b3[0];
#pragma unroll
    for (int j = 0; j < 16; ++j) {
        float mean = h_sum[16 * g + j] * invc;
        unsigned int e = h_max[16 * g + j];
        float mx = (e == 0u) ? 0.0f : (__uint_as_float(e) - 2.0f);
        acc = fmaf(mean, w3[j], fmaf(mx, w3[16 + j], acc));
    }
    out[g] = 1.0f / (1.0f + __expf(-acc));
}

extern "C" void kernel_launch(void* const* d_in, const int* in_sizes, int n_in,
                              void* d_out, int out_size, void* d_ws, size_t ws_size,
                              hipStream_t stream)
{
    const float* x   = (const float*)d_in[0];
    const int*   ei  = (const int*)d_in[1];   // row = ei, col = ei + NE
    const int*   bat = (const int*)d_in[2];
    const float* w1  = (const float*)d_in[3];
    const float* b1  = (const float*)d_in[4];
    const float* w2  = (const float*)d_in[5];
    const float* b2  = (const float*)d_in[6];
    const float* w3  = (const float*)d_in[7];
    const float* b3  = (const float*)d_in[8];
    float* out = (float*)d_out;

    char* ws = (char*)d_ws;
    size_t off = 0;
    // --- zeroed region (one small memset, ~0.57 MB) ---
    int* binCursor = (int*)(ws + off);         off += 16384;                 // NB ints, padded
    float* h_sum  = (float*)(ws + off);        off += (size_t)NG * 16 * 4;
    unsigned int* h_max = (unsigned int*)(ws + off); off += (size_t)NG * 16 * 4;
    int* cnt      = (int*)(ws + off);          off += (size_t)NG * 4;
    size_t zero_bytes = off;
    // --- non-zeroed scratch (total ~41 MB) ---
    unsigned int* pack = (unsigned int*)(ws + off); off += (size_t)NB * CAP * 4; // 32 MB
    __half* xh    = (__half*)(ws + off);       off += (size_t)NN * 4 * 2;    // 8 MB

    hipMemsetAsync(d_ws, 0, zero_bytes, stream);

    bin_scatter_k<<<BIN_BLOCKS, 1024, 0, stream>>>(ei, ei + NE, x, binCursor, pack, xh);
    bucket_agg_k<<<(NB + 3) / 4, 256, 0, stream>>>(pack, binCursor, xh, bat,
                                                   w1, b1, w2, b2, h_sum, h_max, cnt);
    out_k<<<(NG + 255) / 256, 256, 0, stream>>>(h_sum, h_max, cnt, w3, b3, out);
}

// Round 21
// 193.614 us; speedup vs baseline: 1.5010x; 1.5010x over previous
//
#include <hip/hip_runtime.h>
#include <hip/hip_bf16.h>
#include <hip/hip_fp16.h>

static constexpr int NN = 1000000;   // nodes
static constexpr int NE = 5000000;   // edges
static constexpr int NG = 4096;      // graphs
static constexpr int BIN_SH = 9;                      // 512 nodes per bin (halves scatter write-RMW)
static constexpr int BIN_SZ = 1 << BIN_SH;            // 512
static constexpr int NB = (NN + BIN_SZ - 1) >> BIN_SH;   // 1954 (last bin = 64 nodes, %64==0)
static constexpr int CAP_SH = 12;                     // 4096 edge slots per bin (Poisson 2560 + 30 sigma)
static constexpr int CAP = 1 << CAP_SH;
static constexpr int EPB = 16384;                     // edges per block for the scatter pass
static constexpr int EPW = EPB / 1024;                // 16 edges per thread in scatter
static constexpr int BIN_BLOCKS = (NE + EPB - 1) / EPB;  // 306 (1024-thread blocks)
static constexpr int CHUNK = 512;                     // edges per LDS chunk
static constexpr float KEXP = 2.8853900817779268f;    // 2*log2(e): tanh(v)=1-2/(2^(K v)+1)

__device__ __forceinline__ float exp2_fast(float x) {
#if __has_builtin(__builtin_amdgcn_exp2f)
    return __builtin_amdgcn_exp2f(x);
#else
    return exp2f(x);
#endif
}

// tanh from pre-scaled argument s = KEXP * v: tanh(v) = 1 - 2/(2^s + 1).
__device__ __forceinline__ float tanh_scaled(float s) {
    float e = exp2_fast(s);
    return fmaf(-2.0f, __frcp_rn(e + 1.0f), 1.0f);
}

// full-precision tanh for the node-phase (argument not pre-scaled)
__device__ __forceinline__ float fast_tanh(float x) {
    float e = __expf(2.0f * x);
    return 1.0f - 2.0f * __fdividef(1.0f, e + 1.0f);
}

// ---- Pass 1: x->fp16 pack (grid-stride prologue) + scatter (rl,col) into bins ----
// pack[bin*CAP + k] = (rl << 20) | col  (rl < 512 -> 9 bits at 20..28; col < 2^20).
__global__ __launch_bounds__(1024) void bin_scatter_k(
    const int* __restrict__ row, const int* __restrict__ col,
    const float* __restrict__ x,
    int* __restrict__ binCursor, unsigned int* __restrict__ pack,
    __half* __restrict__ xh)
{
    __shared__ int hist[NB];          // 7.8 KB
    // x -> fp16x4 pack (independent of the edge phase; consumed by bucket_agg)
    for (int i = blockIdx.x * 1024 + threadIdx.x; i < NN; i += BIN_BLOCKS * 1024) {
        union { __half2 h2[2]; uint2 u; } o;
        o.h2[0] = __floats2half2_rn(x[3 * i + 0], x[3 * i + 1]);
        o.h2[1] = __floats2half2_rn(x[3 * i + 2], 0.0f);
        *reinterpret_cast<uint2*>(xh + 4 * (size_t)i) = o.u;
    }

    for (int i = threadIdx.x; i < NB; i += 1024) hist[i] = 0;
    __syncthreads();
    int base = blockIdx.x * EPB;

    int r[EPW], c[EPW];
    bool val[EPW];
#pragma unroll
    for (int k = 0; k < EPW; ++k) {
        int e = base + k * 1024 + threadIdx.x;
        val[k] = e < NE;
        r[k] = val[k] ? row[e] : 0;
        c[k] = val[k] ? col[e] : 0;
    }
#pragma unroll
    for (int k = 0; k < EPW; ++k)
        if (val[k]) atomicAdd(&hist[r[k] >> BIN_SH], 1);
    __syncthreads();
    // hist[bin] becomes this block's ABSOLUTE write cursor for that bin
    for (int i = threadIdx.x; i < NB; i += 1024) {
        int cc = hist[i];
        hist[i] = cc ? ((i << CAP_SH) + atomicAdd(&binCursor[i], cc)) : 0;
    }
    __syncthreads();
    int pos[EPW];
#pragma unroll
    for (int k = 0; k < EPW; ++k)
        if (val[k]) pos[k] = atomicAdd(&hist[r[k] >> BIN_SH], 1);   // 16 outstanding
#pragma unroll
    for (int k = 0; k < EPW; ++k)
        if (val[k]) pack[pos[k]] = ((unsigned int)(r[k] & (BIN_SZ - 1)) << 20)
                                   | (unsigned int)c[k];
}

// prefetch one chunk's pack entries + xh gathers into named registers
#define PREFETCH_CHUNK(CS2, GX0, GX1, RL0, RL1)                                   \
    {                                                                             \
        RL0 = RL1 = -1;                                                           \
        int cs2_ = (CS2);                                                         \
        if (cs2_ < ee) {                                                          \
            int mm_ = min(CHUNK, ee - cs2_);                                      \
            int o0_ = tid, o1_ = 256 + tid;                                       \
            if (o0_ < mm_) {                                                      \
                unsigned int p_ = pack[cs2_ + o0_];                               \
                RL0 = (int)(p_ >> 20);                                            \
                GX0 = *reinterpret_cast<const uint2*>(xh + 4 * (size_t)(p_ & 0xFFFFFu)); \
            }                                                                     \
            if (o1_ < mm_) {                                                      \
                unsigned int p_ = pack[cs2_ + o1_];                               \
                RL1 = (int)(p_ >> 20);                                            \
                GX1 = *reinterpret_cast<const uint2*>(xh + 4 * (size_t)(p_ & 0xFFFFFu)); \
            }                                                                     \
        }                                                                         \
    }

// ---- Pass 2: per-bin (512 nodes) chunked pipeline, early-issue prefetch ----
// Thread t owns nodes {t, 256+t}; pooling runs 2 wave-rounds (both %64-aligned).
__global__ __launch_bounds__(256) void bucket_agg_k(
    const unsigned int* __restrict__ pack,
    const int* __restrict__ binCursor,   // final per-bin counts
    const __half* __restrict__ xh,  // [NN,4]
    const int* __restrict__ batch,
    const float* __restrict__ w1,   // [3,16]
    const float* __restrict__ b1,   // [16]
    const float* __restrict__ w2,   // [16,16]
    const float* __restrict__ b2,   // [16]
    float* __restrict__ h_sum,      // [NG,16]
    unsigned int* __restrict__ h_max, // [NG,16] monotone-encoded
    int* __restrict__ cnt)          // [NG]
{
    __shared__ uint4 pay[CHUNK * 2];   // 16 KB sorted h1-payloads (16 halfs/edge)
    __shared__ int scnt[BIN_SZ];       // 2 KB hist -> cursor
    __shared__ int sstart[BIN_SZ];     // 2 KB exclusive starts
    __shared__ int wsum[4];            // per-wave scan sums

    int tid = threadIdx.x;
    int lane = tid & 63, wid = tid >> 6;
    int b = blockIdx.x;
    int nodeBase = b << BIN_SH;
    int nNodes = min(BIN_SZ, NN - nodeBase);   // 512, or 64 for last bin (%64==0)
    int es = b << CAP_SH;
    int ee = es + binCursor[b];

    // one-time: bias pre-scaled by KEXP
    float b1s[16];
#pragma unroll
    for (int j = 0; j < 16; ++j) b1s[j] = b1[j] * KEXP;

    __half2 acc[2][8];                  // node 256k+tid -> acc[k][*]
#pragma unroll
    for (int k = 0; k < 2; ++k)
#pragma unroll
        for (int q = 0; q < 8; ++q) acc[k][q] = __half2half2(__float2half(0.0f));
    int dg[2] = {0, 0};

    // prefetch chunk 0
    uint2 gxA0, gxA1;
    int rlA0, rlA1;
    PREFETCH_CHUNK(es, gxA0, gxA1, rlA0, rlA1);

    for (int cs = es; cs < ee; cs += CHUNK) {
        int m = min(CHUNK, ee - cs);
        *reinterpret_cast<int2*>(&scnt[2 * tid]) = make_int2(0, 0);
        __syncthreads();                                   // B1

        // histogram current chunk from prefetched rl
        if (rlA0 >= 0) atomicAdd(&scnt[rlA0], 1);          // no-return ds_add
        if (rlA1 >= 0) atomicAdd(&scnt[rlA1], 1);

        // prefetch next chunk NOW: loads span scan+MLP+sort+owner phases
        uint2 gxB0, gxB1;
        int rlB0, rlB1;
        PREFETCH_CHUNK(cs + CHUNK, gxB0, gxB1, rlB0, rlB1);
        __syncthreads();                                   // B2

        // exclusive scan of scnt[512] (2 buckets/thread + wave shuffles)
        int2 v2 = *reinterpret_cast<int2*>(&scnt[2 * tid]);
        int tsum = v2.x + v2.y;
        int sc = tsum;
#pragma unroll
        for (int off = 1; off < 64; off <<= 1) {
            int u = __shfl_up(sc, off);
            if (lane >= off) sc += u;
        }
        if (lane == 63) wsum[wid] = sc;
        __syncthreads();                                   // B3
        int pre = 0;
#pragma unroll
        for (int w = 0; w < 4; ++w) pre += (w < wid) ? wsum[w] : 0;
        int ex = pre + sc - tsum;
        int2 st;
        st.x = ex;
        st.y = ex + v2.x;
        *reinterpret_cast<int2*>(&sstart[2 * tid]) = st;
        *reinterpret_cast<int2*>(&scnt[2 * tid]) = st;     // becomes cursor
        __syncthreads();                                   // B4

        // EDGE-PARALLEL MLP1 + tanh (pre-scaled args), then counting-sort scatter
#pragma unroll
        for (int k = 0; k < 2; ++k) {
            int rlk = k ? rlA1 : rlA0;
            if (rlk >= 0) {
                union { uint2 u; __half2 h2[2]; } xi;
                xi.u = k ? gxA1 : gxA0;
                float2 x01 = __half22float2(xi.h2[0]);
                float xs0 = x01.x * KEXP;
                float xs1 = x01.y * KEXP;
                float xs2 = __low2float(xi.h2[1]) * KEXP;
                union { __half2 h2[8]; uint4 u[2]; } o;
#pragma unroll
                for (int q = 0; q < 8; ++q) {
                    float va = fmaf(xs2, w1[32 + 2 * q], fmaf(xs1, w1[16 + 2 * q],
                               fmaf(xs0, w1[2 * q], b1s[2 * q])));
                    float vb = fmaf(xs2, w1[33 + 2 * q], fmaf(xs1, w1[17 + 2 * q],
                               fmaf(xs0, w1[2 * q + 1], b1s[2 * q + 1])));
                    o.h2[q] = __floats2half2_rn(tanh_scaled(va), tanh_scaled(vb));
                }
                int pos = atomicAdd(&scnt[rlk], 1);   // returning ds_add_rtn
                pay[2 * pos + 0] = o.u[0];
                pay[2 * pos + 1] = o.u[1];
            }
        }
        __syncthreads();                                   // B5

        // owner accumulation: thread tid owns nodes {tid, 256+tid}
#pragma unroll
        for (int k = 0; k < 2; ++k) {
            int node = 256 * k + tid;
            if (node < nNodes) {
                int s0 = sstart[node];
                int e0 = (node < BIN_SZ - 1) ? sstart[node + 1] : m;
                dg[k] += e0 - s0;
                for (int e = s0; e < e0; ++e) {
                    union { uint4 u; __half2 h2[4]; } ua, ub;
                    ua.u = pay[2 * e + 0];
                    ub.u = pay[2 * e + 1];
#pragma unroll
                    for (int q = 0; q < 4; ++q) {
                        acc[k][q] = __hadd2(acc[k][q], ua.h2[q]);
                        acc[k][4 + q] = __hadd2(acc[k][4 + q], ub.h2[q]);
                    }
                }
            }
        }
        __syncthreads();                                   // B6

        gxA0 = gxB0; gxA1 = gxB1; rlA0 = rlB0; rlA1 = rlB1;
    }

    // node phase: 2 rounds; round k = nodes 256k+tid, acc slot k
#pragma unroll
    for (int k = 0; k < 2; ++k) {
        if (256 * k >= nNodes) break;                      // wave-uniform
        if (tid < nNodes - 256 * k) {                      // whole waves (nNodes%64==0)
            float af[16];
#pragma unroll
            for (int q = 0; q < 8; ++q) {
                float2 f = __half22float2(acc[k][q]);
                af[2 * q + 0] = f.x;
                af[2 * q + 1] = f.y;
            }
            float inv = 1.0f / fmaxf((float)dg[k], 1.0f);
            float s[16];
#pragma unroll
            for (int j = 0; j < 16; ++j) s[j] = b2[j];
#pragma unroll
            for (int kk = 0; kk < 16; ++kk) {
                float a = af[kk] * inv;
#pragma unroll
                for (int j = 0; j < 16; ++j) s[j] = fmaf(a, w2[16 * kk + j], s[j]);
            }
            float mx[16];
#pragma unroll
            for (int j = 0; j < 16; ++j) { s[j] = fast_tanh(s[j]); mx[j] = s[j]; }

            int g = batch[nodeBase + 256 * k + tid];
            int gp = __shfl_up(g, 1);
            int head = (lane == 0) || (g != gp);
            unsigned long long hm = __ballot(head != 0);

            int f = head;
#pragma unroll
            for (int off = 1; off < 64; off <<= 1) {
                int fu = __shfl_up(f, off);
                bool take = (lane >= off) && (f == 0);
#pragma unroll
                for (int j = 0; j < 16; ++j) {
                    float su = __shfl_up(s[j], off);
                    float mu = __shfl_up(mx[j], off);
                    if (take) { s[j] += su; mx[j] = fmaxf(mx[j], mu); }
                }
                if (lane >= off) f |= fu;
            }

            int hnext = __shfl_down(head, 1);
            bool is_last = (lane == 63) || (hnext != 0);
            if (is_last) {
                unsigned long long below = hm & (~0ULL >> (63 - lane));
                int start = 63 - __clzll(below);
                int seglen = lane - start + 1;
#pragma unroll
                for (int j = 0; j < 16; ++j) {
                    unsafeAtomicAdd(&h_sum[16 * g + j], s[j]);
                    atomicMax(&h_max[16 * g + j], __float_as_uint(mx[j] + 2.0f));
                }
                atomicAdd(&cnt[g], seglen);
            }
        }
    }
}

// ---- Pass 3: head ----
__global__ __launch_bounds__(256) void out_k(
    const float* __restrict__ h_sum,
    const unsigned int* __restrict__ h_max,
    const int* __restrict__ cnt,
    const float* __restrict__ w3,   // [32]
    const float* __restrict__ b3,   // [1]
    float* __restrict__ out)        // [NG]
{
    int g = blockIdx.x * 256 + threadIdx.x;
    if (g >= NG) return;
    float invc = 1.0f / fmaxf((float)cnt[g], 1.0f);
    float acc = b3[0];
#pragma unroll
    for (int j = 0; j < 16; ++j) {
        float mean = h_sum[16 * g + j] * invc;
        unsigned int e = h_max[16 * g + j];
        float mx = (e == 0u) ? 0.0f : (__uint_as_float(e) - 2.0f);
        acc = fmaf(mean, w3[j], fmaf(mx, w3[16 + j], acc));
    }
    out[g] = 1.0f / (1.0f + __expf(-acc));
}

extern "C" void kernel_launch(void* const* d_in, const int* in_sizes, int n_in,
                              void* d_out, int out_size, void* d_ws, size_t ws_size,
                              hipStream_t stream)
{
    const float* x   = (const float*)d_in[0];
    const int*   ei  = (const int*)d_in[1];   // row = ei, col = ei + NE
    const int*   bat = (const int*)d_in[2];
    const float* w1  = (const float*)d_in[3];
    const float* b1  = (const float*)d_in[4];
    const float* w2  = (const float*)d_in[5];
    const float* b2  = (const float*)d_in[6];
    const float* w3  = (const float*)d_in[7];
    const float* b3  = (const float*)d_in[8];
    float* out = (float*)d_out;

    char* ws = (char*)d_ws;
    size_t off = 0;
    // --- zeroed region (one small memset, ~0.55 MB) ---
    int* binCursor = (int*)(ws + off);         off += 8192;                  // NB ints, padded
    float* h_sum  = (float*)(ws + off);        off += (size_t)NG * 16 * 4;
    unsigned int* h_max = (unsigned int*)(ws + off); off += (size_t)NG * 16 * 4;
    int* cnt      = (int*)(ws + off);          off += (size_t)NG * 4;
    size_t zero_bytes = off;
    // --- non-zeroed scratch (total ~41 MB) ---
    unsigned int* pack = (unsigned int*)(ws + off); off += (size_t)NB * CAP * 4; // 32 MB
    __half* xh    = (__half*)(ws + off);       off += (size_t)NN * 4 * 2;    // 8 MB

    hipMemsetAsync(d_ws, 0, zero_bytes, stream);

    bin_scatter_k<<<BIN_BLOCKS, 1024, 0, stream>>>(ei, ei + NE, x, binCursor, pack, xh);
    bucket_agg_k<<<NB, 256, 0, stream>>>(pack, binCursor, xh, bat,
                                         w1, b1, w2, b2, h_sum, h_max, cnt);
    out_k<<<(NG + 255) / 256, 256, 0, stream>>>(h_sum, h_max, cnt, w3, b3, out);
}

// Round 22
// 188.029 us; speedup vs baseline: 1.5456x; 1.0297x over previous
//
#include <hip/hip_runtime.h>
#include <hip/hip_bf16.h>
#include <hip/hip_fp16.h>

static constexpr int NN = 1000000;   // nodes
static constexpr int NE = 5000000;   // edges
static constexpr int NG = 4096;      // graphs
static constexpr int BIN_SH = 8;                      // 256 nodes per bin
static constexpr int BIN_SZ = 1 << BIN_SH;            // 256
static constexpr int NB = (NN + BIN_SZ - 1) >> BIN_SH;   // 3907 (last bin = 64 nodes, %64==0)
static constexpr int CAP_SH = 11;                     // 2048 edge slots per bin
static constexpr int CAP = 1 << CAP_SH;
static constexpr int EPB = 8192;                      // edges per block: 612 blocks -> 2.4/CU balance
static constexpr int EPW = EPB / 1024;                // 8 edges per thread in scatter
static constexpr int BIN_BLOCKS = (NE + EPB - 1) / EPB;  // 611 (1024-thread blocks)
static constexpr int CHUNK = 512;                     // edges per LDS chunk (18 KB -> 8 blocks/CU)
static constexpr float KEXP = 2.8853900817779268f;    // 2*log2(e): tanh(v)=1-2/(2^(K v)+1)

__device__ __forceinline__ float exp2_fast(float x) {
#if __has_builtin(__builtin_amdgcn_exp2f)
    return __builtin_amdgcn_exp2f(x);
#else
    return exp2f(x);
#endif
}

// tanh from pre-scaled argument s = KEXP * v: tanh(v) = 1 - 2/(2^s + 1).
__device__ __forceinline__ float tanh_scaled(float s) {
    float e = exp2_fast(s);
    return fmaf(-2.0f, __frcp_rn(e + 1.0f), 1.0f);
}

// full-precision tanh for the node-phase (argument not pre-scaled)
__device__ __forceinline__ float fast_tanh(float x) {
    float e = __expf(2.0f * x);
    return 1.0f - 2.0f * __fdividef(1.0f, e + 1.0f);
}

// ---- Pass 1: x->fp16 pack (grid-stride prologue) + scatter (rl,col) into bins ----
__global__ __launch_bounds__(1024) void bin_scatter_k(
    const int* __restrict__ row, const int* __restrict__ col,
    const float* __restrict__ x,
    int* __restrict__ binCursor, unsigned int* __restrict__ pack,
    __half* __restrict__ xh)
{
    __shared__ int hist[NB];          // 15.6 KB -> 2 blocks/CU
    // x -> fp16x4 pack (independent of the edge phase; consumed by bucket_agg)
    for (int i = blockIdx.x * 1024 + threadIdx.x; i < NN; i += BIN_BLOCKS * 1024) {
        union { __half2 h2[2]; uint2 u; } o;
        o.h2[0] = __floats2half2_rn(x[3 * i + 0], x[3 * i + 1]);
        o.h2[1] = __floats2half2_rn(x[3 * i + 2], 0.0f);
        *reinterpret_cast<uint2*>(xh + 4 * (size_t)i) = o.u;
    }

    for (int i = threadIdx.x; i < NB; i += 1024) hist[i] = 0;
    __syncthreads();
    int base = blockIdx.x * EPB;

    int r[EPW], c[EPW];
    bool val[EPW];
#pragma unroll
    for (int k = 0; k < EPW; ++k) {
        int e = base + k * 1024 + threadIdx.x;
        val[k] = e < NE;
        r[k] = val[k] ? row[e] : 0;
        c[k] = val[k] ? col[e] : 0;
    }
#pragma unroll
    for (int k = 0; k < EPW; ++k)
        if (val[k]) atomicAdd(&hist[r[k] >> BIN_SH], 1);
    __syncthreads();
    // hist[bin] becomes this block's ABSOLUTE write cursor for that bin
    for (int i = threadIdx.x; i < NB; i += 1024) {
        int cc = hist[i];
        hist[i] = cc ? ((i << CAP_SH) + atomicAdd(&binCursor[i], cc)) : 0;
    }
    __syncthreads();
    int pos[EPW];
#pragma unroll
    for (int k = 0; k < EPW; ++k)
        if (val[k]) pos[k] = atomicAdd(&hist[r[k] >> BIN_SH], 1);   // 8 outstanding
#pragma unroll
    for (int k = 0; k < EPW; ++k)
        if (val[k]) pack[pos[k]] = ((unsigned int)(r[k] & (BIN_SZ - 1)) << 20)
                                   | (unsigned int)c[k];
}

// prefetch one chunk's pack entries + xh gathers into named registers
#define PREFETCH_CHUNK(CS2, GX0, GX1, RL0, RL1)                                   \
    {                                                                             \
        RL0 = RL1 = -1;                                                           \
        int cs2_ = (CS2);                                                         \
        if (cs2_ < ee) {                                                          \
            int mm_ = min(CHUNK, ee - cs2_);                                      \
            int o0_ = tid, o1_ = 256 + tid;                                       \
            if (o0_ < mm_) {                                                      \
                unsigned int p_ = pack[cs2_ + o0_];                               \
                RL0 = (int)(p_ >> 20);                                            \
                GX0 = *reinterpret_cast<const uint2*>(xh + 4 * (size_t)(p_ & 0xFFFFFu)); \
            }                                                                     \
            if (o1_ < mm_) {                                                      \
                unsigned int p_ = pack[cs2_ + o1_];                               \
                RL1 = (int)(p_ >> 20);                                            \
                GX1 = *reinterpret_cast<const uint2*>(xh + 4 * (size_t)(p_ & 0xFFFFFu)); \
            }                                                                     \
        }                                                                         \
    }

// ---- Pass 2: per-bin chunked pipeline, early-issue prefetch (round-17 best) ----
__global__ __launch_bounds__(256) void bucket_agg_k(
    const unsigned int* __restrict__ pack,
    const int* __restrict__ binCursor,   // final per-bin counts
    const __half* __restrict__ xh,  // [NN,4]
    const int* __restrict__ batch,
    const float* __restrict__ w1,   // [3,16]
    const float* __restrict__ b1,   // [16]
    const float* __restrict__ w2,   // [16,16]
    const float* __restrict__ b2,   // [16]
    float* __restrict__ h_sum,      // [NG,16]
    unsigned int* __restrict__ h_max, // [NG,16] monotone-encoded
    int* __restrict__ cnt)          // [NG]
{
    __shared__ uint4 pay[CHUNK * 2];   // 16 KB sorted h1-payloads (16 halfs/edge)
    __shared__ int scnt[BIN_SZ];       // hist -> cursor
    __shared__ int sstart[BIN_SZ];     // exclusive starts
    __shared__ int wsum[4];            // per-wave scan sums

    int tid = threadIdx.x;
    int lane = tid & 63, wid = tid >> 6;
    int b = blockIdx.x;
    int nodeBase = b << BIN_SH;
    int nNodes = min(BIN_SZ, NN - nodeBase);   // 256, or 64 for last bin (%64==0)
    int es = b << CAP_SH;
    int ee = es + binCursor[b];

    // one-time: bias pre-scaled by KEXP (16 VGPR)
    float b1s[16];
#pragma unroll
    for (int j = 0; j < 16; ++j) b1s[j] = b1[j] * KEXP;

    __half2 acc8[8];
#pragma unroll
    for (int q = 0; q < 8; ++q) acc8[q] = __half2half2(__float2half(0.0f));
    int dg = 0;

    // prefetch chunk 0
    uint2 gxA0, gxA1;
    int rlA0, rlA1;
    PREFETCH_CHUNK(es, gxA0, gxA1, rlA0, rlA1);

    for (int cs = es; cs < ee; cs += CHUNK) {
        int m = min(CHUNK, ee - cs);
        scnt[tid] = 0;
        __syncthreads();                                   // B1

        // histogram current chunk from prefetched rl
        if (rlA0 >= 0) atomicAdd(&scnt[rlA0], 1);          // no-return ds_add
        if (rlA1 >= 0) atomicAdd(&scnt[rlA1], 1);

        // prefetch next chunk NOW: loads span scan+MLP+sort+owner phases
        uint2 gxB0, gxB1;
        int rlB0, rlB1;
        PREFETCH_CHUNK(cs + CHUNK, gxB0, gxB1, rlB0, rlB1);
        __syncthreads();                                   // B2

        // exclusive scan of scnt via wave shuffles
        int v = scnt[tid];
        int sc = v;
#pragma unroll
        for (int off = 1; off < 64; off <<= 1) {
            int u = __shfl_up(sc, off);
            if (lane >= off) sc += u;
        }
        if (lane == 63) wsum[wid] = sc;
        __syncthreads();                                   // B3
        int pre = 0;
#pragma unroll
        for (int w = 0; w < 4; ++w) pre += (w < wid) ? wsum[w] : 0;
        int ex = pre + sc - v;
        sstart[tid] = ex;
        scnt[tid] = ex;
        __syncthreads();                                   // B4

        // EDGE-PARALLEL MLP1 + tanh (pre-scaled args), then counting-sort scatter
#pragma unroll
        for (int k = 0; k < 2; ++k) {
            int rlk = k ? rlA1 : rlA0;
            if (rlk >= 0) {
                union { uint2 u; __half2 h2[2]; } xi;
                xi.u = k ? gxA1 : gxA0;
                float2 x01 = __half22float2(xi.h2[0]);
                float xs0 = x01.x * KEXP;
                float xs1 = x01.y * KEXP;
                float xs2 = __low2float(xi.h2[1]) * KEXP;
                union { __half2 h2[8]; uint4 u[2]; } o;
#pragma unroll
                for (int q = 0; q < 8; ++q) {
                    float va = fmaf(xs2, w1[32 + 2 * q], fmaf(xs1, w1[16 + 2 * q],
                               fmaf(xs0, w1[2 * q], b1s[2 * q])));
                    float vb = fmaf(xs2, w1[33 + 2 * q], fmaf(xs1, w1[17 + 2 * q],
                               fmaf(xs0, w1[2 * q + 1], b1s[2 * q + 1])));
                    o.h2[q] = __floats2half2_rn(tanh_scaled(va), tanh_scaled(vb));
                }
                int pos = atomicAdd(&scnt[rlk], 1);   // returning ds_add_rtn
                pay[2 * pos + 0] = o.u[0];
                pay[2 * pos + 1] = o.u[1];
            }
        }
        __syncthreads();                                   // B5

        // owner accumulation: thread tid owns node tid; 8 pk_add_f16 per edge
        if (tid < nNodes) {
            int s0 = sstart[tid];
            int e0 = (tid < 255) ? sstart[tid + 1] : m;
            dg += e0 - s0;
            for (int e = s0; e < e0; ++e) {
                union { uint4 u; __half2 h2[4]; } ua, ub;
                ua.u = pay[2 * e + 0];
                ub.u = pay[2 * e + 1];
#pragma unroll
                for (int q = 0; q < 4; ++q) {
                    acc8[q] = __hadd2(acc8[q], ua.h2[q]);
                    acc8[4 + q] = __hadd2(acc8[4 + q], ub.h2[q]);
                }
            }
        }
        __syncthreads();                                   // B6

        gxA0 = gxB0; gxA1 = gxB1; rlA0 = rlB0; rlA1 = rlB1;
    }

    // node phase: normalize, MLP2, tanh, segmented wave reduction over sorted batch
    if (tid < nNodes) {                       // wave-uniform (nNodes % 64 == 0)
        float acc[16];
#pragma unroll
        for (int q = 0; q < 8; ++q) {
            float2 f = __half22float2(acc8[q]);
            acc[2 * q + 0] = f.x;
            acc[2 * q + 1] = f.y;
        }
        float inv = 1.0f / fmaxf((float)dg, 1.0f);
        float s[16];
#pragma unroll
        for (int j = 0; j < 16; ++j) s[j] = b2[j];
#pragma unroll
        for (int k = 0; k < 16; ++k) {
            float a = acc[k] * inv;
#pragma unroll
            for (int j = 0; j < 16; ++j) s[j] = fmaf(a, w2[16 * k + j], s[j]);
        }
        float m[16];
#pragma unroll
        for (int j = 0; j < 16; ++j) { s[j] = fast_tanh(s[j]); m[j] = s[j]; }

        int g = batch[nodeBase + tid];
        int gp = __shfl_up(g, 1);
        int head = (lane == 0) || (g != gp);
        unsigned long long hm = __ballot(head != 0);

        int f = head;
#pragma unroll
        for (int off = 1; off < 64; off <<= 1) {
            int fu = __shfl_up(f, off);
            bool take = (lane >= off) && (f == 0);
#pragma unroll
            for (int j = 0; j < 16; ++j) {
                float su = __shfl_up(s[j], off);
                float mu = __shfl_up(m[j], off);
                if (take) { s[j] += su; m[j] = fmaxf(m[j], mu); }
            }
            if (lane >= off) f |= fu;
        }

        int hnext = __shfl_down(head, 1);
        bool is_last = (lane == 63) || (hnext != 0);
        if (is_last) {
            unsigned long long below = hm & (~0ULL >> (63 - lane));
            int start = 63 - __clzll(below);
            int seglen = lane - start + 1;
#pragma unroll
            for (int j = 0; j < 16; ++j) {
                unsafeAtomicAdd(&h_sum[16 * g + j], s[j]);
                atomicMax(&h_max[16 * g + j], __float_as_uint(m[j] + 2.0f));
            }
            atomicAdd(&cnt[g], seglen);
        }
    }
}

// ---- Pass 3: head ----
__global__ __launch_bounds__(256) void out_k(
    const float* __restrict__ h_sum,
    const unsigned int* __restrict__ h_max,
    const int* __restrict__ cnt,
    const float* __restrict__ w3,   // [32]
    const float* __restrict__ b3,   // [1]
    float* __restrict__ out)        // [NG]
{
    int g = blockIdx.x * 256 + threadIdx.x;
    if (g >= NG) return;
    float invc = 1.0f / fmaxf((float)cnt[g], 1.0f);
    float acc = b3[0];
#pragma unroll
    for (int j = 0; j < 16; ++j) {
        float mean = h_sum[16 * g + j] * invc;
        unsigned int e = h_max[16 * g + j];
        float mx = (e == 0u) ? 0.0f : (__uint_as_float(e) - 2.0f);
        acc = fmaf(mean, w3[j], fmaf(mx, w3[16 + j], acc));
    }
    out[g] = 1.0f / (1.0f + __expf(-acc));
}

extern "C" void kernel_launch(void* const* d_in, const int* in_sizes, int n_in,
                              void* d_out, int out_size, void* d_ws, size_t ws_size,
                              hipStream_t stream)
{
    const float* x   = (const float*)d_in[0];
    const int*   ei  = (const int*)d_in[1];   // row = ei, col = ei + NE
    const int*   bat = (const int*)d_in[2];
    const float* w1  = (const float*)d_in[3];
    const float* b1  = (const float*)d_in[4];
    const float* w2  = (const float*)d_in[5];
    const float* b2  = (const float*)d_in[6];
    const float* w3  = (const float*)d_in[7];
    const float* b3  = (const float*)d_in[8];
    float* out = (float*)d_out;

    char* ws = (char*)d_ws;
    size_t off = 0;
    // --- zeroed region (one small memset, ~0.57 MB) ---
    int* binCursor = (int*)(ws + off);         off += 16384;                 // NB ints, padded
    float* h_sum  = (float*)(ws + off);        off += (size_t)NG * 16 * 4;
    unsigned int* h_max = (unsigned int*)(ws + off); off += (size_t)NG * 16 * 4;
    int* cnt      = (int*)(ws + off);          off += (size_t)NG * 4;
    size_t zero_bytes = off;
    // --- non-zeroed scratch (total ~41 MB) ---
    unsigned int* pack = (unsigned int*)(ws + off); off += (size_t)NB * CAP * 4; // 32 MB
    __half* xh    = (__half*)(ws + off);       off += (size_t)NN * 4 * 2;    // 8 MB

    hipMemsetAsync(d_ws, 0, zero_bytes, stream);

    bin_scatter_k<<<BIN_BLOCKS, 1024, 0, stream>>>(ei, ei + NE, x, binCursor, pack, xh);
    bucket_agg_k<<<NB, 256, 0, stream>>>(pack, binCursor, xh, bat,
                                         w1, b1, w2, b2, h_sum, h_max, cnt);
    out_k<<<(NG + 255) / 256, 256, 0, stream>>>(h_sum, h_max, cnt, w3, b3, out);
}

// Round 23
// 183.133 us; speedup vs baseline: 1.5869x; 1.0267x over previous
//
#include <hip/hip_runtime.h>
#include <hip/hip_bf16.h>
#include <hip/hip_fp16.h>

static constexpr int NN = 1000000;   // nodes
static constexpr int NE = 5000000;   // edges
static constexpr int NG = 4096;      // graphs
static constexpr int BIN_SH = 8;                      // 256 nodes per bin
static constexpr int BIN_SZ = 1 << BIN_SH;            // 256
static constexpr int NB = (NN + BIN_SZ - 1) >> BIN_SH;   // 3907 (last bin = 64 nodes, %64==0)
static constexpr int CAP_SH = 11;                     // 2048 edge slots per bin
static constexpr int CAP = 1 << CAP_SH;
static constexpr int EPB = 16384;                     // edges per block for the scatter pass
static constexpr int EPW = EPB / 1024;                // 16 edges per thread in scatter
static constexpr int BIN_BLOCKS = (NE + EPB - 1) / EPB;  // 306 (1024-thread blocks)
static constexpr int CHUNK = 512;                     // edges per LDS chunk (18 KB -> 8 blocks/CU)
static constexpr float KEXP = 2.8853900817779268f;    // 2*log2(e): tanh(v)=1-2/(2^(K v)+1)

__device__ __forceinline__ float exp2_fast(float x) {
#if __has_builtin(__builtin_amdgcn_exp2f)
    return __builtin_amdgcn_exp2f(x);
#else
    return exp2f(x);
#endif
}

// tanh from pre-scaled argument s = KEXP * v: tanh(v) = 1 - 2/(2^s + 1).
__device__ __forceinline__ float tanh_scaled(float s) {
    float e = exp2_fast(s);
    return fmaf(-2.0f, __frcp_rn(e + 1.0f), 1.0f);
}

// full-precision tanh for the node-phase (argument not pre-scaled)
__device__ __forceinline__ float fast_tanh(float x) {
    float e = __expf(2.0f * x);
    return 1.0f - 2.0f * __fdividef(1.0f, e + 1.0f);
}

// ---- Pass 1: x->fp16 pack (grid-stride prologue) + scatter (rl,col) into bins ----
__global__ __launch_bounds__(1024) void bin_scatter_k(
    const int* __restrict__ row, const int* __restrict__ col,
    const float* __restrict__ x,
    int* __restrict__ binCursor, unsigned int* __restrict__ pack,
    __half* __restrict__ xh)
{
    __shared__ int hist[NB];          // 15.6 KB -> 2 blocks/CU
    // x -> fp16x4 pack (independent of the edge phase; consumed by bucket_agg)
    for (int i = blockIdx.x * 1024 + threadIdx.x; i < NN; i += BIN_BLOCKS * 1024) {
        union { __half2 h2[2]; uint2 u; } o;
        o.h2[0] = __floats2half2_rn(x[3 * i + 0], x[3 * i + 1]);
        o.h2[1] = __floats2half2_rn(x[3 * i + 2], 0.0f);
        *reinterpret_cast<uint2*>(xh + 4 * (size_t)i) = o.u;
    }

    for (int i = threadIdx.x; i < NB; i += 1024) hist[i] = 0;
    __syncthreads();
    int base = blockIdx.x * EPB;

    int r[EPW], c[EPW];
    bool val[EPW];
#pragma unroll
    for (int k = 0; k < EPW; ++k) {
        int e = base + k * 1024 + threadIdx.x;
        val[k] = e < NE;
        r[k] = val[k] ? row[e] : 0;
        c[k] = val[k] ? col[e] : 0;
    }
#pragma unroll
    for (int k = 0; k < EPW; ++k)
        if (val[k]) atomicAdd(&hist[r[k] >> BIN_SH], 1);
    __syncthreads();
    // hist[bin] becomes this block's ABSOLUTE write cursor for that bin
    for (int i = threadIdx.x; i < NB; i += 1024) {
        int cc = hist[i];
        hist[i] = cc ? ((i << CAP_SH) + atomicAdd(&binCursor[i], cc)) : 0;
    }
    __syncthreads();
    int pos[EPW];
#pragma unroll
    for (int k = 0; k < EPW; ++k)
        if (val[k]) pos[k] = atomicAdd(&hist[r[k] >> BIN_SH], 1);   // 16 outstanding
#pragma unroll
    for (int k = 0; k < EPW; ++k)
        if (val[k]) pack[pos[k]] = ((unsigned int)(r[k] & (BIN_SZ - 1)) << 20)
                                   | (unsigned int)c[k];
}

// prefetch one chunk's pack entries + xh gathers into named registers
#define PREFETCH_CHUNK(CS2, GX0, GX1, RL0, RL1)                                   \
    {                                                                             \
        RL0 = RL1 = -1;                                                           \
        int cs2_ = (CS2);                                                         \
        if (cs2_ < ee) {                                                          \
            int mm_ = min(CHUNK, ee - cs2_);                                      \
            int o0_ = tid, o1_ = 256 + tid;                                       \
            if (o0_ < mm_) {                                                      \
                unsigned int p_ = pack[cs2_ + o0_];                               \
                RL0 = (int)(p_ >> 20);                                            \
                GX0 = *reinterpret_cast<const uint2*>(xh + 4 * (size_t)(p_ & 0xFFFFFu)); \
            }                                                                     \
            if (o1_ < mm_) {                                                      \
                unsigned int p_ = pack[cs2_ + o1_];                               \
                RL1 = (int)(p_ >> 20);                                            \
                GX1 = *reinterpret_cast<const uint2*>(xh + 4 * (size_t)(p_ & 0xFFFFFu)); \
            }                                                                     \
        }                                                                         \
    }

// ---- Pass 2: per-bin chunked pipeline, early-issue prefetch (round-17 best) ----
__global__ __launch_bounds__(256) void bucket_agg_k(
    const unsigned int* __restrict__ pack,
    const int* __restrict__ binCursor,   // final per-bin counts
    const __half* __restrict__ xh,  // [NN,4]
    const int* __restrict__ batch,
    const float* __restrict__ w1,   // [3,16]
    const float* __restrict__ b1,   // [16]
    const float* __restrict__ w2,   // [16,16]
    const float* __restrict__ b2,   // [16]
    float* __restrict__ h_sum,      // [NG,16]
    unsigned int* __restrict__ h_max, // [NG,16] monotone-encoded
    int* __restrict__ cnt)          // [NG]
{
    __shared__ uint4 pay[CHUNK * 2];   // 16 KB sorted h1-payloads (16 halfs/edge)
    __shared__ int scnt[BIN_SZ];       // hist -> cursor
    __shared__ int sstart[BIN_SZ];     // exclusive starts
    __shared__ int wsum[4];            // per-wave scan sums

    int tid = threadIdx.x;
    int lane = tid & 63, wid = tid >> 6;
    int b = blockIdx.x;
    int nodeBase = b << BIN_SH;
    int nNodes = min(BIN_SZ, NN - nodeBase);   // 256, or 64 for last bin (%64==0)
    int es = b << CAP_SH;
    int ee = es + binCursor[b];

    // one-time: bias pre-scaled by KEXP (16 VGPR)
    float b1s[16];
#pragma unroll
    for (int j = 0; j < 16; ++j) b1s[j] = b1[j] * KEXP;

    __half2 acc8[8];
#pragma unroll
    for (int q = 0; q < 8; ++q) acc8[q] = __half2half2(__float2half(0.0f));
    int dg = 0;

    // prefetch chunk 0
    uint2 gxA0, gxA1;
    int rlA0, rlA1;
    PREFETCH_CHUNK(es, gxA0, gxA1, rlA0, rlA1);

    for (int cs = es; cs < ee; cs += CHUNK) {
        int m = min(CHUNK, ee - cs);
        scnt[tid] = 0;
        __syncthreads();                                   // B1

        // histogram current chunk from prefetched rl
        if (rlA0 >= 0) atomicAdd(&scnt[rlA0], 1);          // no-return ds_add
        if (rlA1 >= 0) atomicAdd(&scnt[rlA1], 1);

        // prefetch next chunk NOW: loads span scan+MLP+sort+owner phases
        uint2 gxB0, gxB1;
        int rlB0, rlB1;
        PREFETCH_CHUNK(cs + CHUNK, gxB0, gxB1, rlB0, rlB1);
        __syncthreads();                                   // B2

        // exclusive scan of scnt via wave shuffles
        int v = scnt[tid];
        int sc = v;
#pragma unroll
        for (int off = 1; off < 64; off <<= 1) {
            int u = __shfl_up(sc, off);
            if (lane >= off) sc += u;
        }
        if (lane == 63) wsum[wid] = sc;
        __syncthreads();                                   // B3
        int pre = 0;
#pragma unroll
        for (int w = 0; w < 4; ++w) pre += (w < wid) ? wsum[w] : 0;
        int ex = pre + sc - v;
        sstart[tid] = ex;
        scnt[tid] = ex;
        __syncthreads();                                   // B4

        // EDGE-PARALLEL MLP1 + tanh (pre-scaled args), then counting-sort scatter
#pragma unroll
        for (int k = 0; k < 2; ++k) {
            int rlk = k ? rlA1 : rlA0;
            if (rlk >= 0) {
                union { uint2 u; __half2 h2[2]; } xi;
                xi.u = k ? gxA1 : gxA0;
                float2 x01 = __half22float2(xi.h2[0]);
                float xs0 = x01.x * KEXP;
                float xs1 = x01.y * KEXP;
                float xs2 = __low2float(xi.h2[1]) * KEXP;
                union { __half2 h2[8]; uint4 u[2]; } o;
#pragma unroll
                for (int q = 0; q < 8; ++q) {
                    float va = fmaf(xs2, w1[32 + 2 * q], fmaf(xs1, w1[16 + 2 * q],
                               fmaf(xs0, w1[2 * q], b1s[2 * q])));
                    float vb = fmaf(xs2, w1[33 + 2 * q], fmaf(xs1, w1[17 + 2 * q],
                               fmaf(xs0, w1[2 * q + 1], b1s[2 * q + 1])));
                    o.h2[q] = __floats2half2_rn(tanh_scaled(va), tanh_scaled(vb));
                }
                int pos = atomicAdd(&scnt[rlk], 1);   // returning ds_add_rtn
                pay[2 * pos + 0] = o.u[0];
                pay[2 * pos + 1] = o.u[1];
            }
        }
        __syncthreads();                                   // B5

        // owner accumulation: thread tid owns node tid; 8 pk_add_f16 per edge
        if (tid < nNodes) {
            int s0 = sstart[tid];
            int e0 = (tid < 255) ? sstart[tid + 1] : m;
            dg += e0 - s0;
            for (int e = s0; e < e0; ++e) {
                union { uint4 u; __half2 h2[4]; } ua, ub;
                ua.u = pay[2 * e + 0];
                ub.u = pay[2 * e + 1];
#pragma unroll
                for (int q = 0; q < 4; ++q) {
                    acc8[q] = __hadd2(acc8[q], ua.h2[q]);
                    acc8[4 + q] = __hadd2(acc8[4 + q], ub.h2[q]);
                }
            }
        }
        __syncthreads();                                   // B6

        gxA0 = gxB0; gxA1 = gxB1; rlA0 = rlB0; rlA1 = rlB1;
    }

    // node phase: normalize, MLP2, tanh, segmented wave reduction over sorted batch
    if (tid < nNodes) {                       // wave-uniform (nNodes % 64 == 0)
        float acc[16];
#pragma unroll
        for (int q = 0; q < 8; ++q) {
            float2 f = __half22float2(acc8[q]);
            acc[2 * q + 0] = f.x;
            acc[2 * q + 1] = f.y;
        }
        float inv = 1.0f / fmaxf((float)dg, 1.0f);
        float s[16];
#pragma unroll
        for (int j = 0; j < 16; ++j) s[j] = b2[j];
#pragma unroll
        for (int k = 0; k < 16; ++k) {
            float a = acc[k] * inv;
#pragma unroll
            for (int j = 0; j < 16; ++j) s[j] = fmaf(a, w2[16 * k + j], s[j]);
        }
        float m[16];
#pragma unroll
        for (int j = 0; j < 16; ++j) { s[j] = fast_tanh(s[j]); m[j] = s[j]; }

        int g = batch[nodeBase + tid];
        int gp = __shfl_up(g, 1);
        int head = (lane == 0) || (g != gp);
        unsigned long long hm = __ballot(head != 0);

        int f = head;
#pragma unroll
        for (int off = 1; off < 64; off <<= 1) {
            int fu = __shfl_up(f, off);
            bool take = (lane >= off) && (f == 0);
#pragma unroll
            for (int j = 0; j < 16; ++j) {
                float su = __shfl_up(s[j], off);
                float mu = __shfl_up(m[j], off);
                if (take) { s[j] += su; m[j] = fmaxf(m[j], mu); }
            }
            if (lane >= off) f |= fu;
        }

        int hnext = __shfl_down(head, 1);
        bool is_last = (lane == 63) || (hnext != 0);
        if (is_last) {
            unsigned long long below = hm & (~0ULL >> (63 - lane));
            int start = 63 - __clzll(below);
            int seglen = lane - start + 1;
#pragma unroll
            for (int j = 0; j < 16; ++j) {
                unsafeAtomicAdd(&h_sum[16 * g + j], s[j]);
                atomicMax(&h_max[16 * g + j], __float_as_uint(m[j] + 2.0f));
            }
            atomicAdd(&cnt[g], seglen);
        }
    }
}

// ---- Pass 3: head ----
__global__ __launch_bounds__(256) void out_k(
    const float* __restrict__ h_sum,
    const unsigned int* __restrict__ h_max,
    const int* __restrict__ cnt,
    const float* __restrict__ w3,   // [32]
    const float* __restrict__ b3,   // [1]
    float* __restrict__ out)        // [NG]
{
    int g = blockIdx.x * 256 + threadIdx.x;
    if (g >= NG) return;
    float invc = 1.0f / fmaxf((float)cnt[g], 1.0f);
    float acc = b3[0];
#pragma unroll
    for (int j = 0; j < 16; ++j) {
        float mean = h_sum[16 * g + j] * invc;
        unsigned int e = h_max[16 * g + j];
        float mx = (e == 0u) ? 0.0f : (__uint_as_float(e) - 2.0f);
        acc = fmaf(mean, w3[j], fmaf(mx, w3[16 + j], acc));
    }
    out[g] = 1.0f / (1.0f + __expf(-acc));
}

extern "C" void kernel_launch(void* const* d_in, const int* in_sizes, int n_in,
                              void* d_out, int out_size, void* d_ws, size_t ws_size,
                              hipStream_t stream)
{
    const float* x   = (const float*)d_in[0];
    const int*   ei  = (const int*)d_in[1];   // row = ei, col = ei + NE
    const int*   bat = (const int*)d_in[2];
    const float* w1  = (const float*)d_in[3];
    const float* b1  = (const float*)d_in[4];
    const float* w2  = (const float*)d_in[5];
    const float* b2  = (const float*)d_in[6];
    const float* w3  = (const float*)d_in[7];
    const float* b3  = (const float*)d_in[8];
    float* out = (float*)d_out;

    char* ws = (char*)d_ws;
    size_t off = 0;
    // --- zeroed region (one small memset, ~0.57 MB) ---
    int* binCursor = (int*)(ws + off);         off += 16384;                 // NB ints, padded
    float* h_sum  = (float*)(ws + off);        off += (size_t)NG * 16 * 4;
    unsigned int* h_max = (unsigned int*)(ws + off); off += (size_t)NG * 16 * 4;
    int* cnt      = (int*)(ws + off);          off += (size_t)NG * 4;
    size_t zero_bytes = off;
    // --- non-zeroed scratch (total ~41 MB) ---
    unsigned int* pack = (unsigned int*)(ws + off); off += (size_t)NB * CAP * 4; // 32 MB
    __half* xh    = (__half*)(ws + off);       off += (size_t)NN * 4 * 2;    // 8 MB

    hipMemsetAsync(d_ws, 0, zero_bytes, stream);

    bin_scatter_k<<<BIN_BLOCKS, 1024, 0, stream>>>(ei, ei + NE, x, binCursor, pack, xh);
    bucket_agg_k<<<NB, 256, 0, stream>>>(pack, binCursor, xh, bat,
                                         w1, b1, w2, b2, h_sum, h_max, cnt);
    out_k<<<(NG + 255) / 256, 256, 0, stream>>>(h_sum, h_max, cnt, w3, b3, out);
}